// Round 1
// baseline (404.666 us; speedup 1.0000x reference)
//
#include <hip/hip_runtime.h>
#include <hip/hip_bf16.h>

typedef __bf16 bf16;
typedef __attribute__((ext_vector_type(8))) __bf16 bf16x8;
typedef __attribute__((ext_vector_type(4))) float f32x4;

#define MFMA16(a, b, c) __builtin_amdgcn_mfma_f32_16x16x32_bf16(a, b, c, 0, 0, 0)

constexpr int Bsz = 2, Pseq = 2048, Mdim = 1024, NH = 16, Dh = 64;
constexpr int ROWS = Bsz * Pseq; // 4096
constexpr float LOG2E = 1.4426950408889634f;
constexpr float BIG_NEG = -3.0e38f;

// ---------------- fp32 -> bf16 convert (x) ----------------
__global__ void k_cvt(const float* __restrict__ X, bf16* __restrict__ Xb, int n4) {
  int i = blockIdx.x * blockDim.x + threadIdx.x;
  int stride = gridDim.x * blockDim.x;
  const f32x4* X4 = (const f32x4*)X;
  for (; i < n4; i += stride) {
    f32x4 v = X4[i];
    union { bf16 h[4]; uint2 u; } pk;
    pk.h[0] = (bf16)v[0]; pk.h[1] = (bf16)v[1];
    pk.h[2] = (bf16)v[2]; pk.h[3] = (bf16)v[3];
    ((uint2*)Xb)[i] = pk.u;
  }
}

// ---------------- W [Kdim][Ndim] fp32 -> Wt [Ndim][Kdim] bf16 ----------------
__global__ void k_transpose_cvt(const float* __restrict__ W, bf16* __restrict__ Wt,
                                int Ndim, int Kdim) {
  __shared__ __align__(16) bf16 tile[64][72];
  int n0 = blockIdx.x * 64, k0 = blockIdx.y * 64;
  int t = threadIdx.x;
  int tc = t & 15, tr = t >> 4;
#pragma unroll
  for (int pass = 0; pass < 4; ++pass) {
    int r = tr + pass * 16;
    f32x4 v = *(const f32x4*)(W + (size_t)(k0 + r) * Ndim + n0 + tc * 4);
#pragma unroll
    for (int i = 0; i < 4; ++i) tile[tc * 4 + i][r] = (bf16)v[i];
  }
  __syncthreads();
#pragma unroll
  for (int pass = 0; pass < 4; ++pass) {
    int n = tr + pass * 16;
    union { bf16 h[4]; uint2 u; } pk;
#pragma unroll
    for (int i = 0; i < 4; ++i) pk.h[i] = tile[n][tc * 4 + i];
    *(uint2*)(Wt + (size_t)(n0 + n) * Kdim + k0 + tc * 4) = pk.u;
  }
}

// ---------------- QKV GEMM: [4096,1024]x[1024,3072] -> Q/K/V [B,H,P,D] bf16 ----------------
__global__ __launch_bounds__(256) void k_qkv(const bf16* __restrict__ Xb,
                                             const bf16* __restrict__ Wt,
                                             const float* __restrict__ bias,
                                             bf16* __restrict__ Qo,
                                             bf16* __restrict__ Ko,
                                             bf16* __restrict__ Vo) {
  int cb = blockIdx.x, rb = blockIdx.y;
  int lane = threadIdx.x & 63, w = threadIdx.x >> 6;
  int l15 = lane & 15, g = lane >> 4;
  int row0 = rb * 128 + w * 32;
  int col0 = cb * 128;

  f32x4 acc[2][8];
  const f32x4 zero = {0.f, 0.f, 0.f, 0.f};
#pragma unroll
  for (int mt = 0; mt < 2; ++mt)
#pragma unroll
    for (int nt = 0; nt < 8; ++nt) acc[mt][nt] = zero;

#pragma unroll 2
  for (int k0 = 0; k0 < Mdim; k0 += 32) {
    bf16x8 af[2], bfr[8];
#pragma unroll
    for (int mt = 0; mt < 2; ++mt)
      af[mt] = *(const bf16x8*)(Xb + (size_t)(row0 + mt * 16 + l15) * Mdim + k0 + g * 8);
#pragma unroll
    for (int nt = 0; nt < 8; ++nt)
      bfr[nt] = *(const bf16x8*)(Wt + (size_t)(col0 + nt * 16 + l15) * Mdim + k0 + g * 8);
#pragma unroll
    for (int mt = 0; mt < 2; ++mt)
#pragma unroll
      for (int nt = 0; nt < 8; ++nt)
        acc[mt][nt] = MFMA16(af[mt], bfr[nt], acc[mt][nt]);
  }

  int sec = col0 >> 10; // 0=q, 1=k, 2=v
  bf16* out = sec == 0 ? Qo : (sec == 1 ? Ko : Vo);
  float scale = (sec == 0) ? 0.125f : 1.0f; // q / sqrt(64)
#pragma unroll
  for (int nt = 0; nt < 8; ++nt) {
    int col = col0 + nt * 16 + l15;
    int cm = col & 1023;
    int h = cm >> 6, d = cm & 63;
    float bv = bias[col];
#pragma unroll
    for (int mt = 0; mt < 2; ++mt) {
#pragma unroll
      for (int r = 0; r < 4; ++r) {
        int row = row0 + mt * 16 + g * 4 + r;
        int b = row >> 11, p = row & 2047;
        float v = (acc[mt][nt][r] + bv) * scale;
        out[(size_t)((b * NH + h) * Pseq + p) * Dh + d] = (bf16)v;
      }
    }
  }
}

// ---------------- causal flash attention: Q,K,V [B,H,P,D] bf16 -> Z [B,P,M] bf16 ----------------
__global__ __launch_bounds__(256) void k_attn(const bf16* __restrict__ Q,
                                              const bf16* __restrict__ K,
                                              const bf16* __restrict__ V,
                                              bf16* __restrict__ Z) {
  __shared__ __align__(16) bf16 Vt[64][136];      // V tile transposed [d][kv], pad 8
  __shared__ __align__(16) bf16 Pb[4][32][136];   // per-wave P [q][kv], pad 8
  int bh = blockIdx.y;
  int qt = (int)gridDim.x - 1 - (int)blockIdx.x;  // heavy tiles first
  int b = bh >> 4, h = bh & 15;
  const bf16* Qb = Q + (size_t)bh * Pseq * Dh;
  const bf16* Kb = K + (size_t)bh * Pseq * Dh;
  const bf16* Vb = V + (size_t)bh * Pseq * Dh;
  int lane = threadIdx.x & 63, w = threadIdx.x >> 6;
  int l15 = lane & 15, g = lane >> 4;

  // Q B-fragments (persist across k-tiles): q = qt*128 + w*32 + nt*16 + l15, d = ks*32 + g*8
  bf16x8 qf[2][2];
#pragma unroll
  for (int nt = 0; nt < 2; ++nt)
#pragma unroll
    for (int ks = 0; ks < 2; ++ks)
      qf[nt][ks] = *(const bf16x8*)(Qb + (size_t)(qt * 128 + w * 32 + nt * 16 + l15) * Dh + ks * 32 + g * 8);

  f32x4 Oacc[2][4];
  const f32x4 zero = {0.f, 0.f, 0.f, 0.f};
#pragma unroll
  for (int mt = 0; mt < 2; ++mt)
#pragma unroll
    for (int nt = 0; nt < 4; ++nt) Oacc[mt][nt] = zero;
  float m_i[2] = {BIG_NEG, BIG_NEG};
  float l_i[2] = {0.f, 0.f};

  for (int j = 0; j <= qt; ++j) {
    // ---- cooperative V-tile stage, transposed into LDS ----
    {
      int kvb = threadIdx.x & 31;
      int d0 = (threadIdx.x >> 5) * 8;
#pragma unroll
      for (int pass = 0; pass < 4; ++pass) {
        int kv = kvb + pass * 32;
        bf16x8 v8 = *(const bf16x8*)(Vb + (size_t)(j * 128 + kv) * Dh + d0);
#pragma unroll
        for (int i = 0; i < 8; ++i) Vt[d0 + i][kv] = v8[i];
      }
    }
    // ---- S^T = K_j . Q^T (fragments direct from global) ----
    f32x4 S[8][2];
#pragma unroll
    for (int mt = 0; mt < 8; ++mt) { S[mt][0] = zero; S[mt][1] = zero; }
#pragma unroll
    for (int ks = 0; ks < 2; ++ks) {
#pragma unroll
      for (int mt = 0; mt < 8; ++mt) {
        bf16x8 kf = *(const bf16x8*)(Kb + (size_t)(j * 128 + mt * 16 + l15) * Dh + ks * 32 + g * 8);
        S[mt][0] = MFMA16(kf, qf[0][ks], S[mt][0]);
        S[mt][1] = MFMA16(kf, qf[1][ks], S[mt][1]);
      }
    }
    __syncthreads(); // V tile visible

    // ---- causal mask on diagonal tile ----
    if (j == qt) {
#pragma unroll
      for (int mt = 0; mt < 8; ++mt)
#pragma unroll
        for (int nt = 0; nt < 2; ++nt)
#pragma unroll
          for (int r = 0; r < 4; ++r) {
            int kv = mt * 16 + g * 4 + r;
            int q = w * 32 + nt * 16 + l15;
            if (kv > q) S[mt][nt][r] = BIG_NEG;
          }
    }

    // ---- online softmax (stats per lane-column; reduce across quads) ----
    float tmax[2] = {BIG_NEG, BIG_NEG};
#pragma unroll
    for (int mt = 0; mt < 8; ++mt)
#pragma unroll
      for (int nt = 0; nt < 2; ++nt)
#pragma unroll
        for (int r = 0; r < 4; ++r) tmax[nt] = fmaxf(tmax[nt], S[mt][nt][r]);
    float mnew[2], alpha[2];
#pragma unroll
    for (int nt = 0; nt < 2; ++nt) {
      tmax[nt] = fmaxf(tmax[nt], __shfl_xor(tmax[nt], 16));
      tmax[nt] = fmaxf(tmax[nt], __shfl_xor(tmax[nt], 32));
      mnew[nt] = fmaxf(m_i[nt], tmax[nt]);
      alpha[nt] = exp2f((m_i[nt] - mnew[nt]) * LOG2E);
    }
    float tsum[2] = {0.f, 0.f};
#pragma unroll
    for (int mt = 0; mt < 8; ++mt)
#pragma unroll
      for (int nt = 0; nt < 2; ++nt) {
        union { bf16 h[4]; uint2 u; } pk;
#pragma unroll
        for (int r = 0; r < 4; ++r) {
          float p = exp2f((S[mt][nt][r] - mnew[nt]) * LOG2E);
          tsum[nt] += p;
          pk.h[r] = (bf16)p;
        }
        *(uint2*)&Pb[w][nt * 16 + l15][mt * 16 + g * 4] = pk.u;
      }
#pragma unroll
    for (int nt = 0; nt < 2; ++nt) {
      tsum[nt] += __shfl_xor(tsum[nt], 16);
      tsum[nt] += __shfl_xor(tsum[nt], 32);
      l_i[nt] = l_i[nt] * alpha[nt] + tsum[nt];
      m_i[nt] = mnew[nt];
    }

    // ---- rescale O by alpha (broadcast col-stats to row-owners) ----
#pragma unroll
    for (int mt = 0; mt < 2; ++mt)
#pragma unroll
      for (int r = 0; r < 4; ++r) {
        float a = __shfl(alpha[mt], g * 4 + r);
#pragma unroll
        for (int nt = 0; nt < 4; ++nt) Oacc[mt][nt][r] *= a;
      }

    // ---- O += P . V  (P from per-wave LDS, V from shared LDS) ----
#pragma unroll
    for (int ks2 = 0; ks2 < 4; ++ks2) {
      bf16x8 pf[2], vf[4];
      pf[0] = *(const bf16x8*)&Pb[w][l15][ks2 * 32 + g * 8];
      pf[1] = *(const bf16x8*)&Pb[w][16 + l15][ks2 * 32 + g * 8];
#pragma unroll
      for (int nt = 0; nt < 4; ++nt)
        vf[nt] = *(const bf16x8*)&Vt[nt * 16 + l15][ks2 * 32 + g * 8];
#pragma unroll
      for (int mt = 0; mt < 2; ++mt)
#pragma unroll
        for (int nt = 0; nt < 4; ++nt)
          Oacc[mt][nt] = MFMA16(pf[mt], vf[nt], Oacc[mt][nt]);
    }
    __syncthreads(); // all V reads done before next stage overwrites
  }

  // ---- epilogue: O /= l, store Z [B,P,M] bf16 ----
#pragma unroll
  for (int mt = 0; mt < 2; ++mt)
#pragma unroll
    for (int r = 0; r < 4; ++r) {
      float li = __shfl(l_i[mt], g * 4 + r);
      float inv = 1.0f / li;
      int qrow = qt * 128 + w * 32 + mt * 16 + g * 4 + r;
      size_t rowbase = ((size_t)(b * Pseq + qrow)) * Mdim + h * Dh;
#pragma unroll
      for (int nt = 0; nt < 4; ++nt)
        Z[rowbase + nt * 16 + l15] = (bf16)(Oacc[mt][nt][r] * inv);
    }
}

// ---------------- proj GEMM: Z [4096,1024] bf16 x Wproj^T -> out fp32 ----------------
__global__ __launch_bounds__(256) void k_proj(const bf16* __restrict__ Zb,
                                              const bf16* __restrict__ Wt,
                                              const float* __restrict__ bias,
                                              float* __restrict__ Out) {
  int cb = blockIdx.x, rb = blockIdx.y;
  int lane = threadIdx.x & 63, w = threadIdx.x >> 6;
  int l15 = lane & 15, g = lane >> 4;
  int row0 = rb * 128 + w * 32;
  int col0 = cb * 128;

  f32x4 acc[2][8];
  const f32x4 zero = {0.f, 0.f, 0.f, 0.f};
#pragma unroll
  for (int mt = 0; mt < 2; ++mt)
#pragma unroll
    for (int nt = 0; nt < 8; ++nt) acc[mt][nt] = zero;

#pragma unroll 2
  for (int k0 = 0; k0 < Mdim; k0 += 32) {
    bf16x8 af[2], bfr[8];
#pragma unroll
    for (int mt = 0; mt < 2; ++mt)
      af[mt] = *(const bf16x8*)(Zb + (size_t)(row0 + mt * 16 + l15) * Mdim + k0 + g * 8);
#pragma unroll
    for (int nt = 0; nt < 8; ++nt)
      bfr[nt] = *(const bf16x8*)(Wt + (size_t)(col0 + nt * 16 + l15) * Mdim + k0 + g * 8);
#pragma unroll
    for (int mt = 0; mt < 2; ++mt)
#pragma unroll
      for (int nt = 0; nt < 8; ++nt)
        acc[mt][nt] = MFMA16(af[mt], bfr[nt], acc[mt][nt]);
  }

#pragma unroll
  for (int nt = 0; nt < 8; ++nt) {
    int col = col0 + nt * 16 + l15;
    float bv = bias[col];
#pragma unroll
    for (int mt = 0; mt < 2; ++mt) {
#pragma unroll
      for (int r = 0; r < 4; ++r) {
        int row = row0 + mt * 16 + g * 4 + r;
        Out[(size_t)row * Mdim + col] = acc[mt][nt][r] + bv;
      }
    }
  }
}

extern "C" void kernel_launch(void* const* d_in, const int* in_sizes, int n_in,
                              void* d_out, int out_size, void* d_ws, size_t ws_size,
                              hipStream_t stream) {
  const float* x = (const float*)d_in[0];
  const float* W_attn = (const float*)d_in[1];
  const float* b_attn = (const float*)d_in[2];
  const float* W_proj = (const float*)d_in[3];
  const float* b_proj = (const float*)d_in[4];
  float* out = (float*)d_out;

  bf16* Xb = (bf16*)d_ws;                               // 4096*1024
  bf16* Wat = Xb + (size_t)ROWS * Mdim;                 // 3072*1024
  bf16* Wpt = Wat + (size_t)3 * Mdim * Mdim;            // 1024*1024
  bf16* Qs = Wpt + (size_t)Mdim * Mdim;                 // 4096*1024 (B,H,P,D)
  bf16* Ks = Qs + (size_t)ROWS * Mdim;
  bf16* Vs = Ks + (size_t)ROWS * Mdim;
  bf16* Zb = Vs + (size_t)ROWS * Mdim;                  // 4096*1024

  k_cvt<<<1024, 256, 0, stream>>>(x, Xb, ROWS * Mdim / 4);
  k_transpose_cvt<<<dim3(3 * Mdim / 64, Mdim / 64), 256, 0, stream>>>(W_attn, Wat, 3 * Mdim, Mdim);
  k_transpose_cvt<<<dim3(Mdim / 64, Mdim / 64), 256, 0, stream>>>(W_proj, Wpt, Mdim, Mdim);
  k_qkv<<<dim3(3 * Mdim / 128, ROWS / 128), 256, 0, stream>>>(Xb, Wat, b_attn, Qs, Ks, Vs);
  k_attn<<<dim3(Pseq / 128, Bsz * NH), 256, 0, stream>>>(Qs, Ks, Vs, Zb);
  k_proj<<<dim3(Mdim / 128, ROWS / 128), 256, 0, stream>>>(Zb, Wpt, b_proj, out);
}

// Round 2
// 215.468 us; speedup vs baseline: 1.8781x; 1.8781x over previous
//
#include <hip/hip_runtime.h>
#include <hip/hip_bf16.h>

typedef __bf16 bf16;
typedef __attribute__((ext_vector_type(8))) __bf16 bf16x8;
typedef __attribute__((ext_vector_type(4))) float f32x4;

#define MFMA16(a, b, c) __builtin_amdgcn_mfma_f32_16x16x32_bf16(a, b, c, 0, 0, 0)
// async global->LDS, 16B per lane; LDS dest = wave-uniform base + lane*16
#define GLL16(gp, lp)                                                          \
  __builtin_amdgcn_global_load_lds(                                            \
      (const __attribute__((address_space(1))) void*)(gp),                     \
      (__attribute__((address_space(3))) void*)(lp), 16, 0, 0)

constexpr int Bsz = 2, Pseq = 2048, Mdim = 1024, NH = 16, Dh = 64;
constexpr int ROWS = Bsz * Pseq; // 4096
constexpr float LOG2E = 1.4426950408889634f;
constexpr float BIG_NEG = -3.0e38f;

// ---------------- fp32 -> bf16 convert (x) ----------------
__global__ void k_cvt(const float* __restrict__ X, bf16* __restrict__ Xb, int n4) {
  int i = blockIdx.x * blockDim.x + threadIdx.x;
  int stride = gridDim.x * blockDim.x;
  const f32x4* X4 = (const f32x4*)X;
  for (; i < n4; i += stride) {
    f32x4 v = X4[i];
    union { bf16 h[4]; uint2 u; } pk;
    pk.h[0] = (bf16)v[0]; pk.h[1] = (bf16)v[1];
    pk.h[2] = (bf16)v[2]; pk.h[3] = (bf16)v[3];
    ((uint2*)Xb)[i] = pk.u;
  }
}

// ---------------- W [Kdim][Ndim] fp32 -> Wt [Ndim][Kdim] bf16 ----------------
__global__ void k_transpose_cvt(const float* __restrict__ W, bf16* __restrict__ Wt,
                                int Ndim, int Kdim) {
  __shared__ __align__(16) bf16 tile[64][72];
  int n0 = blockIdx.x * 64, k0 = blockIdx.y * 64;
  int t = threadIdx.x;
  int tc = t & 15, tr = t >> 4;
#pragma unroll
  for (int pass = 0; pass < 4; ++pass) {
    int r = tr + pass * 16;
    f32x4 v = *(const f32x4*)(W + (size_t)(k0 + r) * Ndim + n0 + tc * 4);
#pragma unroll
    for (int i = 0; i < 4; ++i) tile[tc * 4 + i][r] = (bf16)v[i];
  }
  __syncthreads();
#pragma unroll
  for (int pass = 0; pass < 4; ++pass) {
    int n = tr + pass * 16;
    union { bf16 h[4]; uint2 u; } pk;
#pragma unroll
    for (int i = 0; i < 4; ++i) pk.h[i] = tile[n][tc * 4 + i];
    *(uint2*)(Wt + (size_t)(n0 + n) * Kdim + k0 + tc * 4) = pk.u;
  }
}

// ---------------- m97-style GEMM core: C(128 x TN) = A[M][K] . Bt[N][K]^T ----
// LDS tiles XOR-swizzled in 16B granules so both global_load_lds staging and
// b128 fragment reads are bank-conflict-free. 2x2 waves; BK=64.
template <int TN>
__device__ __forceinline__ void gemm_core(const bf16* __restrict__ A,
                                          const bf16* __restrict__ Bt,
                                          bf16* Ash, bf16* Bsh, int K,
                                          int row0, int col0,
                                          f32x4 (&acc)[4][TN / 32]) {
  constexpr int NT = TN / 32;
  int tid = threadIdx.x;
  int lane = tid & 63, w = tid >> 6;
  int l15 = lane & 15, g = lane >> 4, l7 = lane & 7, l8 = lane >> 3;
  int wm = w & 1, wn = w >> 1;
  // staging: phys granule = p*256 + w*64 + lane -> row = p*32+w*8+(lane>>3),
  // logical k-group = (lane&7) ^ (lane>>3)  (XOR swizzle key = row&7)
  const bf16* Ag = A + (size_t)(row0 + w * 8 + l8) * K + (l7 ^ l8) * 8;
  const bf16* Bg = Bt + (size_t)(col0 + w * 8 + l8) * K + (l7 ^ l8) * 8;
  bf16* Asb = Ash + w * 512;
  bf16* Bsb = Bsh + w * 512;
  for (int k0 = 0; k0 < K; k0 += 64) {
#pragma unroll
    for (int p = 0; p < 4; ++p)
      GLL16(Ag + (size_t)(p * 32) * K + k0, Asb + p * 2048);
#pragma unroll
    for (int p = 0; p < NT; ++p)
      GLL16(Bg + (size_t)(p * 32) * K + k0, Bsb + p * 2048);
    __syncthreads();
#pragma unroll
    for (int ks = 0; ks < 2; ++ks) {
      int swz = ((ks * 4 + g) ^ l7) * 8;
      bf16x8 af[4], bfr[NT];
#pragma unroll
      for (int mt = 0; mt < 4; ++mt)
        af[mt] = *(const bf16x8*)(Ash + (wm * 64 + mt * 16 + l15) * 64 + swz);
#pragma unroll
      for (int nt = 0; nt < NT; ++nt)
        bfr[nt] = *(const bf16x8*)(Bsh + (wn * (TN / 2) + nt * 16 + l15) * 64 + swz);
#pragma unroll
      for (int mt = 0; mt < 4; ++mt)
#pragma unroll
        for (int nt = 0; nt < NT; ++nt)
          acc[mt][nt] = MFMA16(af[mt], bfr[nt], acc[mt][nt]);
    }
    __syncthreads();
  }
}

// ---------------- QKV GEMM -> Q,K [B,H,P,D]; V transposed [B,H,D,P] ----------
__global__ __launch_bounds__(256) void k_qkv(const bf16* __restrict__ Xb,
                                             const bf16* __restrict__ Wt,
                                             const float* __restrict__ bias,
                                             bf16* __restrict__ Qo,
                                             bf16* __restrict__ Ko,
                                             bf16* __restrict__ Vto) {
  __shared__ __align__(16) bf16 Ash[128 * 64], Bsh[128 * 64];
  int cb = blockIdx.x, rb = blockIdx.y;
  int row0 = rb * 128, col0 = cb * 128;
  f32x4 acc[4][4];
  const f32x4 zero = {0.f, 0.f, 0.f, 0.f};
#pragma unroll
  for (int mt = 0; mt < 4; ++mt)
#pragma unroll
    for (int nt = 0; nt < 4; ++nt) acc[mt][nt] = zero;
  gemm_core<128>(Xb, Wt, Ash, Bsh, Mdim, row0, col0, acc);

  int lane = threadIdx.x & 63, w = threadIdx.x >> 6;
  int l15 = lane & 15, g = lane >> 4;
  int wm = w & 1, wn = w >> 1;
  int sec = cb >> 3; // 0=q 1=k 2=v (uniform per block)
  if (sec < 2) {
    bf16* out = sec == 0 ? Qo : Ko;
    float scale = sec == 0 ? 0.125f : 1.0f; // q / sqrt(64)
#pragma unroll
    for (int nt = 0; nt < 4; ++nt) {
      int col = col0 + wn * 64 + nt * 16 + l15;
      int cm = col & 1023;
      int h = cm >> 6, d = cm & 63;
      float bv = bias[col];
#pragma unroll
      for (int mt = 0; mt < 4; ++mt)
#pragma unroll
        for (int r = 0; r < 4; ++r) {
          int row = row0 + wm * 64 + mt * 16 + g * 4 + r;
          int b = row >> 11, p = row & 2047;
          out[(size_t)((b * NH + h) * Pseq + p) * Dh + d] =
              (bf16)((acc[mt][nt][r] + bv) * scale);
        }
    }
  } else {
#pragma unroll
    for (int nt = 0; nt < 4; ++nt) {
      int col = col0 + wn * 64 + nt * 16 + l15;
      int cm = col & 1023;
      int h = cm >> 6, d = cm & 63;
      float bv = bias[col];
#pragma unroll
      for (int mt = 0; mt < 4; ++mt) {
        int row = row0 + wm * 64 + mt * 16 + g * 4;
        int b = row >> 11, p = row & 2047;
        union { bf16 hh[4]; uint2 u; } pk;
#pragma unroll
        for (int r = 0; r < 4; ++r) pk.hh[r] = (bf16)(acc[mt][nt][r] + bv);
        *(uint2*)(Vto + ((size_t)((b * NH + h) * Dh + d)) * Pseq + p) = pk.u;
      }
    }
  }
}

// ---------------- causal flash attention ------------------------------------
// Q,K [B,H,P,D]; Vt [B,H,D,P]; Z [B,P,M]. 64-row q-tiles, 128-kv tiles.
// K: double-buffered LDS via global_load_lds (XOR swizzle), prefetched 1 tile
// ahead -> single barrier/iter. V fragments direct from global (pre-transposed),
// hidden behind softmax. P: per-wave swizzled LDS (no barrier).
__global__ __launch_bounds__(256) void k_attn(const bf16* __restrict__ Q,
                                              const bf16* __restrict__ K,
                                              const bf16* __restrict__ Vt,
                                              bf16* __restrict__ Z) {
  __shared__ __align__(16) bf16 Ksh[2 * 128 * 64]; // 32 KB, [buf][kv][d] swizzled
  __shared__ __align__(16) bf16 Pb[4 * 16 * 128];  // 16 KB, per-wave [q][kv] swizzled
  int bh = blockIdx.x;
  int qt = 31 - (int)blockIdx.y; // heaviest tiles dispatched first
  int b = bh >> 4, h = bh & 15;
  const bf16* Qb = Q + (size_t)bh * Pseq * Dh;
  const bf16* Kb = K + (size_t)bh * Pseq * Dh;
  const bf16* Vb = Vt + (size_t)bh * Dh * Pseq;
  int tid = threadIdx.x;
  int lane = tid & 63, w = tid >> 6;
  int l15 = lane & 15, g = lane >> 4, l7 = lane & 7, l8 = lane >> 3;
  int q0 = qt * 64;
  int njt = qt / 2 + 1; // kv tiles of 128 covering [0, 64*(qt+1))

  // Q B-fragments (persist): q-col = q0 + w*16 + l15, k = ks*32 + g*8
  bf16x8 qf[2];
#pragma unroll
  for (int ks = 0; ks < 2; ++ks)
    qf[ks] = *(const bf16x8*)(Qb + (size_t)(q0 + w * 16 + l15) * Dh + ks * 32 + g * 8);

  f32x4 O[4];
  const f32x4 zero = {0.f, 0.f, 0.f, 0.f};
#pragma unroll
  for (int nt = 0; nt < 4; ++nt) O[nt] = zero;
  float m_i = BIG_NEG, l_i = 0.f;

  const bf16* Kg = Kb + (size_t)(w * 8 + l8) * Dh + (l7 ^ l8) * 8;
  bf16* Pw = Pb + w * 2048;
  const bf16* Vgb = Vb + (size_t)l15 * Pseq + g * 8;

  // prologue: stage K tile 0 into buf 0
#pragma unroll
  for (int p = 0; p < 4; ++p)
    GLL16(Kg + (size_t)(p * 32) * Dh, Ksh + w * 512 + p * 2048);

  for (int j = 0; j < njt; ++j) {
    int buf = j & 1;
    __syncthreads(); // staging of tile j complete; buf^1 reads (iter j-1) done
    if (j + 1 < njt) { // prefetch K tile j+1 into other buffer
      const bf16* Kg2 = Kg + (size_t)((j + 1) * 128) * Dh;
      bf16* dst = Ksh + (buf ^ 1) * 8192 + w * 512;
#pragma unroll
      for (int p = 0; p < 4; ++p)
        GLL16(Kg2 + (size_t)(p * 32) * Dh, dst + p * 2048);
    }
    // ---- S^T = K_j . Q^T ----
    f32x4 S[8];
#pragma unroll
    for (int mt = 0; mt < 8; ++mt) S[mt] = zero;
    const bf16* Kr = Ksh + buf * 8192;
#pragma unroll
    for (int ks = 0; ks < 2; ++ks) {
      int swz = ((ks * 4 + g) ^ l7) * 8;
#pragma unroll
      for (int mt = 0; mt < 8; ++mt) {
        bf16x8 kf = *(const bf16x8*)(Kr + (mt * 16 + l15) * 64 + swz);
        S[mt] = MFMA16(kf, qf[ks], S[mt]);
      }
    }
    // ---- V fragments, first half (latency hidden behind softmax) ----
    const bf16* Vgj = Vgb + (size_t)j * 128;
    bf16x8 vfa[2][4];
#pragma unroll
    for (int ks2 = 0; ks2 < 2; ++ks2)
#pragma unroll
      for (int nt = 0; nt < 4; ++nt)
        vfa[ks2][nt] = *(const bf16x8*)(Vgj + (size_t)(nt * 16) * Pseq + ks2 * 32);

    // ---- causal mask (last tile only) ----
    if (j == njt - 1) {
      int q = q0 + w * 16 + l15;
#pragma unroll
      for (int mt = 0; mt < 8; ++mt) {
        int kvb = j * 128 + mt * 16 + g * 4;
#pragma unroll
        for (int r = 0; r < 4; ++r)
          if (kvb + r > q) S[mt][r] = BIG_NEG;
      }
    }
    // ---- online softmax; lane owns q-col l15 ----
    float tmax = BIG_NEG;
#pragma unroll
    for (int mt = 0; mt < 8; ++mt)
#pragma unroll
      for (int r = 0; r < 4; ++r) tmax = fmaxf(tmax, S[mt][r]);
    tmax = fmaxf(tmax, __shfl_xor(tmax, 16));
    tmax = fmaxf(tmax, __shfl_xor(tmax, 32));
    float mnew = fmaxf(m_i, tmax);
    float alpha = exp2f((m_i - mnew) * LOG2E);
    float tsum = 0.f;
#pragma unroll
    for (int mt = 0; mt < 8; ++mt) {
      union { bf16 hh[4]; uint2 u; } pk;
#pragma unroll
      for (int r = 0; r < 4; ++r) {
        float p = exp2f((S[mt][r] - mnew) * LOG2E);
        tsum += p;
        pk.hh[r] = (bf16)p;
      }
      int pg = (mt * 2 + (g >> 1)) ^ l15; // kv-granule, swizzled by row
      *(uint2*)(Pw + l15 * 128 + pg * 8 + (g & 1) * 4) = pk.u;
    }
    tsum += __shfl_xor(tsum, 16);
    tsum += __shfl_xor(tsum, 32);
    l_i = l_i * alpha + tsum;
    m_i = mnew;
    // ---- V fragments, second half ----
    bf16x8 vfb[2][4];
#pragma unroll
    for (int ks2 = 0; ks2 < 2; ++ks2)
#pragma unroll
      for (int nt = 0; nt < 4; ++nt)
        vfb[ks2][nt] = *(const bf16x8*)(Vgj + (size_t)(nt * 16) * Pseq + 64 + ks2 * 32);
    // ---- rescale O (broadcast col-stats to row-owners) ----
#pragma unroll
    for (int r = 0; r < 4; ++r) {
      float a = __shfl(alpha, g * 4 + r);
#pragma unroll
      for (int nt = 0; nt < 4; ++nt) O[nt][r] *= a;
    }
    // ---- O += P . V ----
#pragma unroll
    for (int ks2 = 0; ks2 < 2; ++ks2) {
      bf16x8 pf = *(const bf16x8*)(Pw + l15 * 128 + (((ks2 * 4 + g) ^ l15) * 8));
#pragma unroll
      for (int nt = 0; nt < 4; ++nt) O[nt] = MFMA16(pf, vfa[ks2][nt], O[nt]);
    }
#pragma unroll
    for (int ks2 = 2; ks2 < 4; ++ks2) {
      bf16x8 pf = *(const bf16x8*)(Pw + l15 * 128 + (((ks2 * 4 + g) ^ l15) * 8));
#pragma unroll
      for (int nt = 0; nt < 4; ++nt) O[nt] = MFMA16(pf, vfb[ks2 - 2][nt], O[nt]);
    }
  }
  // ---- epilogue: O /= l, store Z [B,P,M] bf16 ----
#pragma unroll
  for (int r = 0; r < 4; ++r) {
    float li = __shfl(l_i, g * 4 + r);
    float inv = 1.0f / li;
    int q = q0 + w * 16 + g * 4 + r;
    size_t base = ((size_t)(b * Pseq + q)) * Mdim + h * Dh;
#pragma unroll
    for (int nt = 0; nt < 4; ++nt)
      Z[base + nt * 16 + l15] = (bf16)(O[nt][r] * inv);
  }
}

// ---------------- proj GEMM: Z [4096,1024] bf16 x Wproj^T -> out fp32 --------
__global__ __launch_bounds__(256) void k_proj(const bf16* __restrict__ Zb,
                                              const bf16* __restrict__ Wt,
                                              const float* __restrict__ bias,
                                              float* __restrict__ Out) {
  __shared__ __align__(16) bf16 Ash[128 * 64], Bsh[64 * 64];
  int cb = blockIdx.x, rb = blockIdx.y;
  int row0 = rb * 128, col0 = cb * 64;
  f32x4 acc[4][2];
  const f32x4 zero = {0.f, 0.f, 0.f, 0.f};
#pragma unroll
  for (int mt = 0; mt < 4; ++mt)
#pragma unroll
    for (int nt = 0; nt < 2; ++nt) acc[mt][nt] = zero;
  gemm_core<64>(Zb, Wt, Ash, Bsh, Mdim, row0, col0, acc);

  int lane = threadIdx.x & 63, w = threadIdx.x >> 6;
  int l15 = lane & 15, g = lane >> 4;
  int wm = w & 1, wn = w >> 1;
#pragma unroll
  for (int nt = 0; nt < 2; ++nt) {
    int col = col0 + wn * 32 + nt * 16 + l15;
    float bv = bias[col];
#pragma unroll
    for (int mt = 0; mt < 4; ++mt)
#pragma unroll
      for (int r = 0; r < 4; ++r) {
        int row = row0 + wm * 64 + mt * 16 + g * 4 + r;
        Out[(size_t)row * Mdim + col] = acc[mt][nt][r] + bv;
      }
  }
}

extern "C" void kernel_launch(void* const* d_in, const int* in_sizes, int n_in,
                              void* d_out, int out_size, void* d_ws, size_t ws_size,
                              hipStream_t stream) {
  const float* x = (const float*)d_in[0];
  const float* W_attn = (const float*)d_in[1];
  const float* b_attn = (const float*)d_in[2];
  const float* W_proj = (const float*)d_in[3];
  const float* b_proj = (const float*)d_in[4];
  float* out = (float*)d_out;

  bf16* Xb = (bf16*)d_ws;                    // 4096*1024
  bf16* Wat = Xb + (size_t)ROWS * Mdim;      // 3072*1024
  bf16* Wpt = Wat + (size_t)3 * Mdim * Mdim; // 1024*1024
  bf16* Qs = Wpt + (size_t)Mdim * Mdim;      // [B,H,P,D]
  bf16* Ks = Qs + (size_t)ROWS * Mdim;       // [B,H,P,D]
  bf16* Vts = Ks + (size_t)ROWS * Mdim;      // [B,H,D,P]  (transposed V)
  bf16* Zb = Vts + (size_t)ROWS * Mdim;      // [B,P,M]

  k_cvt<<<1024, 256, 0, stream>>>(x, Xb, ROWS * Mdim / 4);
  k_transpose_cvt<<<dim3(3 * Mdim / 64, Mdim / 64), 256, 0, stream>>>(W_attn, Wat, 3 * Mdim, Mdim);
  k_transpose_cvt<<<dim3(Mdim / 64, Mdim / 64), 256, 0, stream>>>(W_proj, Wpt, Mdim, Mdim);
  k_qkv<<<dim3(3 * Mdim / 128, ROWS / 128), 256, 0, stream>>>(Xb, Wat, b_attn, Qs, Ks, Vts);
  k_attn<<<dim3(Bsz * NH, Pseq / 64), 256, 0, stream>>>(Qs, Ks, Vts, Zb);
  k_proj<<<dim3(Mdim / 64, ROWS / 128), 256, 0, stream>>>(Zb, Wpt, b_proj, out);
}